// Round 3
// baseline (210.390 us; speedup 1.0000x reference)
//
#include <hip/hip_runtime.h>

typedef float f32x4 __attribute__((ext_vector_type(4)));
typedef short bf16x8 __attribute__((ext_vector_type(8)));

// ---- workspace layout (bytes) ----
// B1s: [16 kb][528 cols][128 B]  (bf16, chunk-swizzled; cols 512-519 router, 520-527 zero)
// W2s: [1024 cols][640 B]        (bf16, chunk-swizzled; rows 256-263 = b2, 264-319 zero)
// ACT: [32768 rows][640 B]       (bf16, chunk-swizzled; k 256-263 = p, 264-319 zero)
#define B1S_KBSZ 67584
#define W2S_OFF  1081344
#define ACT_OFF  1736704
// total ws required: 22,708,224 bytes

__device__ __forceinline__ unsigned short f2bf(float f) {
  unsigned int u = __float_as_uint(f);
  return (unsigned short)((u + 0x7FFFu + ((u >> 16) & 1u)) >> 16);
}
__device__ __forceinline__ unsigned int pack2(float a, float b) {
  return (unsigned int)f2bf(a) | ((unsigned int)f2bf(b) << 16);
}
__device__ __forceinline__ unsigned int cvtpk(float a, float b) {
  unsigned int r;
  asm("v_cvt_pk_bf16_f32 %0, %1, %2" : "=v"(r) : "v"(a), "v"(b));
  return r;
}
__device__ __forceinline__ void async16(const void* g, void* l) {
  __builtin_amdgcn_global_load_lds(
      (const __attribute__((address_space(1))) unsigned int*)g,
      (__attribute__((address_space(3))) unsigned int*)l, 16, 0, 0);
}

// ---------------- prep: pack [W1|Wr|0] -> B1s ; [W2;b2;0] -> W2s ----------------
__global__ __launch_bounds__(256) void prep_all(const float* __restrict__ W1,
                                                const float* __restrict__ Wr,
                                                const float* __restrict__ W2,
                                                const float* __restrict__ b2,
                                                unsigned char* __restrict__ B1s,
                                                unsigned char* __restrict__ W2s) {
  if (blockIdx.x < 33) {
    int t = blockIdx.x * 256 + threadIdx.x;
    if (t >= 528 * 16) return;
    int col = t % 528;
    int kb  = t / 528;
    unsigned char* dst = B1s + kb * B1S_KBSZ + col * 128;
    int key = col & 7;
    int e   = col >> 6;
    int hh  = col & 63;
    #pragma unroll
    for (int c = 0; c < 8; ++c) {
      float v[8];
      #pragma unroll
      for (int jj = 0; jj < 8; ++jj) {
        int k = kb * 64 + c * 8 + jj;
        float f;
        if (col < 512)      f = W1[(e * 1024 + k) * 64 + hh];   // W1[e][k][hh]
        else if (col < 520) f = Wr[k * 8 + (col - 512)];        // Wr[k][e]
        else                f = 0.0f;
        v[jj] = f;
      }
      *(uint4*)(dst + ((c ^ key) * 16)) =
          make_uint4(pack2(v[0], v[1]), pack2(v[2], v[3]), pack2(v[4], v[5]), pack2(v[6], v[7]));
    }
  } else {
    int c = (blockIdx.x - 33) * 256 + threadIdx.x;
    if (c >= 1024) return;
    unsigned char* dst = W2s + c * 640;
    int key = c & 7;
    #pragma unroll 1
    for (int cj = 0; cj < 40; ++cj) {
      float v[8];
      #pragma unroll
      for (int jj = 0; jj < 8; ++jj) {
        int k = cj * 8 + jj;
        float f;
        if (k < 256)      f = W2[k * 1024 + c];          // W2[e][h][c], k=e*32+h
        else if (k < 264) f = b2[(k - 256) * 1024 + c];  // b2[e][c]
        else              f = 0.0f;
        v[jj] = f;
      }
      int dstc = (cj & ~7) | ((cj & 7) ^ key);
      *(uint4*)(dst + dstc * 16) =
          make_uint4(pack2(v[0], v[1]), pack2(v[2], v[3]), pack2(v[4], v[5]), pack2(v[6], v[7]));
    }
  }
}

// ---------------- kernel 1: 256x144 tile, dbuf single-drain pipeline ----------------
// grid 512 = 128 M-tiles x 4 pairs; block 512 = 8 waves (4 mg x 2 ng), wave 64x80/64
__global__ __launch_bounds__(512, 2) void moe_gemm1(
    const float* __restrict__ x, const float* __restrict__ br, const float* __restrict__ b1,
    const unsigned char* __restrict__ B1s, unsigned char* __restrict__ ACT) {
  __shared__ __align__(16) unsigned char smem[110592];
  // Bbuf[2]: [0, 36864) ; Abuf[2]: [36864, 102400) ; logit: [102400, 110592)
  float* logit_lds = (float*)(smem + 102400);  // [256][8]

  const int tid  = threadIdx.x;
  const int lane = tid & 63;
  const int w    = tid >> 6;
  const int mg   = w >> 1;   // rows mg*64 .. +64
  const int ng   = w & 1;    // 0: expert-lo frags 0-3 + router frag 8; 1: frags 4-7
  const int f15  = lane & 15;
  const int fhi  = lane >> 4;

  const int wid   = ((blockIdx.x & 7) << 6) + (blockIdx.x >> 3);  // XCD-chunked, 512=8*64
  const int mtile = wid >> 2;
  const int p     = wid & 3;
  const int m0    = mtile << 8;

  f32x4 acc[4][5];
  #pragma unroll
  for (int a = 0; a < 4; ++a)
    #pragma unroll
    for (int b = 0; b < 5; ++b) acc[a][b] = f32x4{0.f, 0.f, 0.f, 0.f};

  // x staging: thread t covers rows {j*64 + (t>>3)}, chunk c = t&7 (8 floats each)
  const int srl = tid >> 3;
  const int sc  = tid & 7;
  const float* xbase = x + (size_t)m0 * 1024 + sc * 8;
  f32x4 areg[8];

  #define LOADX(ks)                                                              \
    {                                                                            \
      _Pragma("unroll")                                                          \
      for (int j = 0; j < 4; ++j) {                                              \
        const float* s = xbase + (size_t)(j * 64 + srl) * 1024 + (ks) * 64;      \
        areg[j * 2]     = *(const f32x4*)s;                                      \
        areg[j * 2 + 1] = *(const f32x4*)(s + 4);                                \
      }                                                                          \
    }
  #define WRITEA(buf)                                                            \
    {                                                                            \
      unsigned char* ab_ = smem + 36864 + (buf) * 32768;                         \
      _Pragma("unroll")                                                          \
      for (int j = 0; j < 4; ++j) {                                              \
        int row = j * 64 + srl;                                                  \
        uint4 u;                                                                 \
        u.x = cvtpk(areg[j * 2].x, areg[j * 2].y);                               \
        u.y = cvtpk(areg[j * 2].z, areg[j * 2].w);                               \
        u.z = cvtpk(areg[j * 2 + 1].x, areg[j * 2 + 1].y);                       \
        u.w = cvtpk(areg[j * 2 + 1].z, areg[j * 2 + 1].w);                       \
        *(uint4*)(ab_ + row * 128 + ((sc ^ (row & 7)) << 4)) = u;                \
      }                                                                          \
    }
  #define STAGEB(ks, buf)                                                        \
    {                                                                            \
      const unsigned char* bsrc_ = B1s + (ks) * B1S_KBSZ;                        \
      unsigned char* bb_ = smem + (buf) * 18432;                                 \
      for (int i = w; i < 18; i += 8) {                                          \
        int gc0 = (i < 16) ? (p * 128 + i * 8) : (512 + (i - 16) * 8);           \
        async16(bsrc_ + gc0 * 128 + lane * 16, bb_ + i * 1024);                  \
      }                                                                          \
    }

  LOADX(0); WRITEA(0); STAGEB(0, 0); LOADX(1);
  __syncthreads();

  int cur = 0;
  #pragma unroll 1
  for (int ks = 0; ks < 16; ++ks) {
    if (ks < 15) {
      STAGEB(ks + 1, cur ^ 1);
      WRITEA(cur ^ 1);
      if (ks < 14) LOADX(ks + 2);
    }
    const unsigned char* ab = smem + 36864 + cur * 32768;
    const unsigned char* bb = smem + cur * 18432;
    #pragma unroll
    for (int ksub = 0; ksub < 2; ++ksub) {
      const int ch = ((ksub * 4 + fhi) ^ (f15 & 7)) << 4;
      bf16x8 af[4];
      #pragma unroll
      for (int mf = 0; mf < 4; ++mf)
        af[mf] = *(const bf16x8*)(ab + (mg * 64 + mf * 16 + f15) * 128 + ch);
      #pragma unroll
      for (int i = 0; i < 4; ++i) {
        bf16x8 bfr = *(const bf16x8*)(bb + ((ng * 4 + i) * 16 + f15) * 128 + ch);
        #pragma unroll
        for (int mf = 0; mf < 4; ++mf)
          acc[mf][i] = __builtin_amdgcn_mfma_f32_16x16x32_bf16(af[mf], bfr, acc[mf][i], 0, 0, 0);
      }
      if (ng == 0) {
        bf16x8 bfr = *(const bf16x8*)(bb + (128 + f15) * 128 + ch);
        #pragma unroll
        for (int mf = 0; mf < 4; ++mf)
          acc[mf][4] = __builtin_amdgcn_mfma_f32_16x16x32_bf16(af[mf], bfr, acc[mf][4], 0, 0, 0);
      }
    }
    __syncthreads();
    cur ^= 1;
  }

  if (ng == 0 && f15 < 8) {  // router logits + br
    float brv = br[f15];
    #pragma unroll
    for (int mf = 0; mf < 4; ++mf)
      #pragma unroll
      for (int r = 0; r < 4; ++r)
        logit_lds[(mg * 64 + mf * 16 + fhi * 4 + r) * 8 + f15] = acc[mf][4][r] + brv;
  }
  __syncthreads();

  const int e = p * 2 + ng;
  const float b1x0 = b1[e * 64 + f15],      b1x1 = b1[e * 64 + 16 + f15];
  const float b1g0 = b1[e * 64 + 32 + f15], b1g1 = b1[e * 64 + 48 + f15];
  unsigned short* hb = (unsigned short*)smem;              // [256][72] shorts (144 B stride)
  unsigned short* pb = (unsigned short*)(smem + 36864);    // [256][8]

  #pragma unroll
  for (int mf = 0; mf < 4; ++mf) {
    #pragma unroll
    for (int r = 0; r < 4; ++r) {
      int row = mg * 64 + mf * 16 + fhi * 4 + r;
      const float* lg = logit_lds + row * 8;
      float l0 = lg[0], l1 = lg[1], l2 = lg[2], l3 = lg[3];
      float l4 = lg[4], l5 = lg[5], l6 = lg[6], l7 = lg[7];
      float mx = fmaxf(fmaxf(fmaxf(l0, l1), fmaxf(l2, l3)),
                       fmaxf(fmaxf(l4, l5), fmaxf(l6, l7)));
      float ssum = __expf(l0 - mx) + __expf(l1 - mx) + __expf(l2 - mx) + __expf(l3 - mx) +
                   __expf(l4 - mx) + __expf(l5 - mx) + __expf(l6 - mx) + __expf(l7 - mx);
      float rinv = 1.f / ssum;
      float pe = __expf(lg[e] - mx) * rinv;
      #pragma unroll
      for (int ci = 0; ci < 2; ++ci) {
        float xv = acc[mf][ci][r]     + (ci ? b1x1 : b1x0);
        float gv = acc[mf][ci + 2][r] + (ci ? b1g1 : b1g0);
        float av = pe * xv * gv / (1.f + __expf(-gv));  // pe * xp * silu(gate)
        hb[row * 72 + ng * 32 + ci * 16 + f15] = f2bf(av);
      }
      if (ng == 0 && f15 < 8) pb[row * 8 + f15] = f2bf(__expf(lg[f15] - mx) * rinv);
    }
  }
  __syncthreads();

  {  // vectorized ACT write
    const int row = tid >> 1, q = tid & 1, key = row & 7;
    unsigned char* arow = ACT + (size_t)(m0 + row) * 640;
    #pragma unroll
    for (int j = 0; j < 4; ++j) {
      int c = q * 4 + j;
      uint4 v = *(const uint4*)((const unsigned char*)hb + row * 144 + c * 16);
      *(uint4*)(arow + p * 128 + ((c ^ key) << 4)) = v;
    }
    if (p == 0) {  // p-append (k 256-263) + zero pad (k 264-319)
      #pragma unroll
      for (int j = 0; j < 4; ++j) {
        int c = q * 4 + j;
        uint4 v = make_uint4(0, 0, 0, 0);
        if (c == 0) v = *(const uint4*)((const unsigned char*)pb + row * 16);
        *(uint4*)(arow + 512 + ((c ^ key) << 4)) = v;
      }
    }
  }
}

// ---------------- kernel 2: ACT[32768,320] @ W2s[320,1024] -> out (f32), dbuf pipeline ----------------
// grid 2048 = 256 m x 8 n; block 256 = 4 waves (2x2), wave 64x64
__global__ __launch_bounds__(256, 2) void moe_gemm2(
    const unsigned char* __restrict__ ACT, const unsigned char* __restrict__ W2s,
    float* __restrict__ out) {
  __shared__ __align__(16) unsigned char smem[65536];  // Abuf[2]: [0,32768) Bbuf[2]: [32768,65536)
  const int tid  = threadIdx.x;
  const int lane = tid & 63;
  const int w    = tid >> 6;
  const int wm   = w >> 1, wn = w & 1;
  const int f15  = lane & 15, fhi = lane >> 4;
  const int r8   = lane >> 3, c8 = lane & 7;

  const int wid = ((blockIdx.x & 7) << 8) + (blockIdx.x >> 3);  // 2048 = 8*256
  const int m0  = (wid >> 3) * 128;
  const int n0  = (wid & 7) * 128;

  f32x4 acc[4][4];
  #pragma unroll
  for (int a = 0; a < 4; ++a)
    #pragma unroll
    for (int b = 0; b < 4; ++b) acc[a][b] = f32x4{0.f, 0.f, 0.f, 0.f};

  #define STAGE2(kb, buf)                                                          \
    {                                                                              \
      for (int i = w; i < 16; i += 4) {                                            \
        async16(ACT + (size_t)(m0 + i * 8 + r8) * 640 + (kb) * 128 + c8 * 16,      \
                smem + (buf) * 16384 + i * 1024);                                  \
        async16(W2s + (size_t)(n0 + i * 8 + r8) * 640 + (kb) * 128 + c8 * 16,      \
                smem + 32768 + (buf) * 16384 + i * 1024);                          \
      }                                                                            \
    }

  STAGE2(0, 0);
  __syncthreads();

  int cur = 0;
  #pragma unroll 1
  for (int kb = 0; kb < 5; ++kb) {
    if (kb < 4) STAGE2(kb + 1, cur ^ 1);
    const unsigned char* ab = smem + cur * 16384;
    const unsigned char* bb = smem + 32768 + cur * 16384;
    #pragma unroll
    for (int ksub = 0; ksub < 2; ++ksub) {
      const int ch = ((ksub * 4 + fhi) ^ (f15 & 7)) << 4;
      bf16x8 af[4];
      #pragma unroll
      for (int mf = 0; mf < 4; ++mf)
        af[mf] = *(const bf16x8*)(ab + (wm * 64 + mf * 16 + f15) * 128 + ch);
      #pragma unroll
      for (int nf = 0; nf < 4; ++nf) {
        bf16x8 bfr = *(const bf16x8*)(bb + (wn * 64 + nf * 16 + f15) * 128 + ch);
        #pragma unroll
        for (int mf = 0; mf < 4; ++mf)
          acc[mf][nf] = __builtin_amdgcn_mfma_f32_16x16x32_bf16(af[mf], bfr, acc[mf][nf], 0, 0, 0);
      }
    }
    __syncthreads();
    cur ^= 1;
  }

  float* ob = out + (size_t)(m0 + wm * 64 + fhi * 4) * 1024 + n0 + wn * 64 + f15;
  #pragma unroll
  for (int mf = 0; mf < 4; ++mf)
    #pragma unroll
    for (int nf = 0; nf < 4; ++nf)
      #pragma unroll
      for (int r = 0; r < 4; ++r)
        ob[(size_t)(mf * 16 + r) * 1024 + nf * 16] = acc[mf][nf][r];
}

extern "C" void kernel_launch(void* const* d_in, const int* in_sizes, int n_in,
                              void* d_out, int out_size, void* d_ws, size_t ws_size,
                              hipStream_t stream) {
  const float* x  = (const float*)d_in[0];
  const float* Wr = (const float*)d_in[1];
  const float* br = (const float*)d_in[2];
  const float* W1 = (const float*)d_in[3];
  const float* b1 = (const float*)d_in[4];
  const float* W2 = (const float*)d_in[5];
  const float* b2 = (const float*)d_in[6];
  float* out = (float*)d_out;
  unsigned char* ws  = (unsigned char*)d_ws;
  unsigned char* B1s = ws;
  unsigned char* W2s = ws + W2S_OFF;
  unsigned char* ACT = ws + ACT_OFF;

  hipLaunchKernelGGL(prep_all, dim3(37), dim3(256), 0, stream, W1, Wr, W2, b2, B1s, W2s);
  hipLaunchKernelGGL(moe_gemm1, dim3(512), dim3(512), 0, stream, x, br, b1, B1s, ACT);
  hipLaunchKernelGGL(moe_gemm2, dim3(2048), dim3(256), 0, stream, ACT, W2s, out);
}